// Round 1
// baseline (240.217 us; speedup 1.0000x reference)
//
#include <hip/hip_runtime.h>
#include <float.h>

// Problem constants (from setup_inputs): x:(10,64,128,256) f32,
// record_len=[5,5], pairwise_t_matrix:(2,5,5,2,3) f32, indicator:(10,) i32.
// Output: (2,64,128,256) f32.
constexpr int C  = 64;
constexpr int H  = 128;
constexpr int W  = 256;
constexpr int HW = H * W;

// Bilinear sample of one channel plane at (ix, iy), zero outside bounds,
// matching the reference's clip-then-mask gather.
__device__ __forceinline__ float bilin(const float* __restrict__ plane,
                                       float ix, float iy) {
  float x0f = floorf(ix), y0f = floorf(iy);
  float wx = ix - x0f, wy = iy - y0f;
  int x0 = (int)x0f, y0 = (int)y0f;
  int x1 = x0 + 1, y1 = y0 + 1;
  float mx0 = (x0 >= 0 && x0 < W) ? 1.0f : 0.0f;
  float mx1 = (x1 >= 0 && x1 < W) ? 1.0f : 0.0f;
  float my0 = (y0 >= 0 && y0 < H) ? 1.0f : 0.0f;
  float my1 = (y1 >= 0 && y1 < H) ? 1.0f : 0.0f;
  int cx0 = min(max(x0, 0), W - 1);
  int cx1 = min(max(x1, 0), W - 1);
  int cy0 = min(max(y0, 0), H - 1);
  int cy1 = min(max(y1, 0), H - 1);
  float v00 = plane[cy0 * W + cx0] * (my0 * mx0);
  float v01 = plane[cy0 * W + cx1] * (my0 * mx1);
  float v10 = plane[cy1 * W + cx0] * (my1 * mx0);
  float v11 = plane[cy1 * W + cx1] * (my1 * mx1);
  return v00 * (1.0f - wx) * (1.0f - wy) + v01 * wx * (1.0f - wy)
       + v10 * (1.0f - wx) * wy          + v11 * wx * wy;
}

// Batch 0: warp-affine agents 0..4, masked channelwise max into
// lidar[HW][64] and cam[HW][64] (pixel-major so attention reads are
// contiguous per pixel).
__global__ __launch_bounds__(256) void warp_max_b0(
    const float* __restrict__ x, const float* __restrict__ tmat,
    const int* __restrict__ ind,
    float* __restrict__ lidar, float* __restrict__ cam) {
  int t = blockIdx.x * 256 + threadIdx.x;
  int c = t & (C - 1);
  int p = t >> 6;            // pixel 0..32767
  int w = p & (W - 1);
  int h = p >> 8;
  float xs = (2.0f * w + 1.0f) / (float)W - 1.0f;
  float ys = (2.0f * h + 1.0f) / (float)H - 1.0f;
  float lid = -FLT_MAX, cm = -FLT_MAX;
#pragma unroll
  for (int n = 0; n < 5; ++n) {
    // pairwise_t_matrix[b=0, i=0, j=n] : 6 floats
    const float* M = tmat + n * 6;
    float gx = M[0] * xs + M[1] * ys + M[2];
    float gy = M[3] * xs + M[4] * ys + M[5];
    float ix = ((gx + 1.0f) * (float)W - 1.0f) * 0.5f;
    float iy = ((gy + 1.0f) * (float)H - 1.0f) * 0.5f;
    const float* plane = x + (size_t)(n * C + c) * HW;
    float v = bilin(plane, ix, iy);
    if (ind[n]) lid = fmaxf(lid, v); else cm = fmaxf(cm, v);
  }
  lidar[p * C + c] = lid;
  cam[p * C + c]   = cm;
}

// Batch 0 attention: one wave per pixel, lane = channel.
// keys r=(dxi*3+dyi): key[c] = cam[(c-dx)%C, (h-dy)%H, w]  (rolls on (C,H)).
__global__ __launch_bounds__(256) void attn_b0(
    const float* __restrict__ lidar, const float* __restrict__ cam,
    float* __restrict__ out) {
  int p    = (blockIdx.x * 256 + threadIdx.x) >> 6;   // pixel
  int lane = threadIdx.x & 63;                        // channel
  int w = p & (W - 1);
  int h = p >> 8;

  float q = lidar[p * C + lane];

  float row[3];
#pragma unroll
  for (int dyi = 0; dyi < 3; ++dyi) {
    int dy = dyi - 1;
    int hh = (h - dy + H) & (H - 1);
    row[dyi] = cam[(hh * W + w) * C + lane];
  }

  float key[9];
#pragma unroll
  for (int dxi = 0; dxi < 3; ++dxi) {
    int dx = dxi - 1;
    int sl = (lane - dx) & 63;   // lane holding channel (c-dx)%64
#pragma unroll
    for (int dyi = 0; dyi < 3; ++dyi)
      key[dxi * 3 + dyi] = __shfl(row[dyi], sl);
  }

  float s[9];
#pragma unroll
  for (int r = 0; r < 9; ++r) s[r] = q * key[r];
#pragma unroll
  for (int m = 1; m < 64; m <<= 1) {
#pragma unroll
    for (int r = 0; r < 9; ++r) s[r] += __shfl_xor(s[r], m);
  }
  // scale = 1/sqrt(64)
#pragma unroll
  for (int r = 0; r < 9; ++r) s[r] *= 0.125f;

  float mx = s[0];
#pragma unroll
  for (int r = 1; r < 9; ++r) mx = fmaxf(mx, s[r]);
  float e[9], sum = 0.0f;
#pragma unroll
  for (int r = 0; r < 9; ++r) { e[r] = __expf(s[r] - mx); sum += e[r]; }
  float inv = 1.0f / sum;

  float o = 0.0f;
#pragma unroll
  for (int r = 0; r < 9; ++r) o += e[r] * inv * key[r];

  out[(size_t)lane * HW + p] = fmaxf(o, q);   // batch 0 slab, (C,H,W) layout
}

// Batch 1 (all lidar): fused warp + 5-way self-attention (row 0 only).
__global__ __launch_bounds__(256) void attn_b1(
    const float* __restrict__ x, const float* __restrict__ tmat,
    float* __restrict__ out) {
  int p    = (blockIdx.x * 256 + threadIdx.x) >> 6;
  int lane = threadIdx.x & 63;                        // channel
  int w = p & (W - 1);
  int h = p >> 8;
  float xs = (2.0f * w + 1.0f) / (float)W - 1.0f;
  float ys = (2.0f * h + 1.0f) / (float)H - 1.0f;

  float v[5];
#pragma unroll
  for (int j = 0; j < 5; ++j) {
    // pairwise_t_matrix[b=1, i=0, j] : offset ((1*5+0)*5 + j)*6
    const float* M = tmat + (25 + j) * 6;
    float gx = M[0] * xs + M[1] * ys + M[2];
    float gy = M[3] * xs + M[4] * ys + M[5];
    float ix = ((gx + 1.0f) * (float)W - 1.0f) * 0.5f;
    float iy = ((gy + 1.0f) * (float)H - 1.0f) * 0.5f;
    const float* plane = x + (size_t)((5 + j) * C + lane) * HW;
    v[j] = bilin(plane, ix, iy);
  }

  float s[5];
#pragma unroll
  for (int j = 0; j < 5; ++j) s[j] = v[0] * v[j];
#pragma unroll
  for (int m = 1; m < 64; m <<= 1) {
#pragma unroll
    for (int j = 0; j < 5; ++j) s[j] += __shfl_xor(s[j], m);
  }
#pragma unroll
  for (int j = 0; j < 5; ++j) s[j] *= 0.125f;

  float mx = s[0];
#pragma unroll
  for (int j = 1; j < 5; ++j) mx = fmaxf(mx, s[j]);
  float e[5], sum = 0.0f;
#pragma unroll
  for (int j = 0; j < 5; ++j) { e[j] = __expf(s[j] - mx); sum += e[j]; }
  float inv = 1.0f / sum;

  float o = 0.0f;
#pragma unroll
  for (int j = 0; j < 5; ++j) o += e[j] * inv * v[j];

  out[(size_t)C * HW + (size_t)lane * HW + p] = o;   // batch 1 slab
}

extern "C" void kernel_launch(void* const* d_in, const int* in_sizes, int n_in,
                              void* d_out, int out_size, void* d_ws, size_t ws_size,
                              hipStream_t stream) {
  const float* x    = (const float*)d_in[0];
  const float* tmat = (const float*)d_in[2];
  const int*   ind  = (const int*)d_in[3];
  float* out = (float*)d_out;

  float* lidar = (float*)d_ws;          //  8 MB
  float* cam   = lidar + (size_t)HW * C; //  8 MB

  // 64 ch * 32768 px = 2,097,152 threads -> 8192 blocks of 256
  warp_max_b0<<<8192, 256, 0, stream>>>(x, tmat, ind, lidar, cam);
  attn_b0<<<8192, 256, 0, stream>>>(lidar, cam, out);
  attn_b1<<<8192, 256, 0, stream>>>(x, tmat, out);
}

// Round 2
// 93.795 us; speedup vs baseline: 2.5611x; 2.5611x over previous
//
#include <hip/hip_runtime.h>
#include <hip/hip_bf16.h>
#include <float.h>

// x:(10,64,128,256) f32, record_len=[5,5], pairwise_t_matrix:(2,5,5,2,3) f32,
// indicator:(10,) i32.  Output: (2,64,128,256) f32.
constexpr int C  = 64;
constexpr int H  = 128;
constexpr int W  = 256;
constexpr int HW = H * W;

// ---------------------------------------------------------------------------
// Transpose x[a0+a][c][p] (f32 channel-major) -> xt[a][p][c] (bf16 pixel-major)
// 64ch x 64px tile per block, 512 tiles/agent, 5 agents => 2560 blocks.
// ---------------------------------------------------------------------------
__global__ __launch_bounds__(256) void transpose_cp(
    const float* __restrict__ x, __hip_bfloat16* __restrict__ xt, int a0) {
  __shared__ float tile[64][65];
  int blk = blockIdx.x;
  int a   = blk >> 9;         // /512
  int t   = blk & 511;
  int p0  = t << 6;           // *64
  int tx  = threadIdx.x & 63;
  int ty  = threadIdx.x >> 6; // 0..3
  const float* src = x + (size_t)(a0 + a) * C * HW;
#pragma unroll
  for (int i = 0; i < 16; ++i) {
    int c = ty * 16 + i;
    tile[c][tx] = src[(size_t)c * HW + p0 + tx];   // 256B coalesced read
  }
  __syncthreads();
  __hip_bfloat16* dst = xt + ((size_t)a * HW + p0) * C;
#pragma unroll
  for (int i = 0; i < 16; ++i) {
    int px = ty * 16 + i;
    // lane == channel -> 128B coalesced bf16 write; tile[tx][px]: stride-65
    // rows => conflict-free column read
    dst[(size_t)px * C + tx] = __float2bfloat16(tile[tx][px]);
  }
}

// Bilinear sample from pixel-major bf16 plane; zero outside bounds
// (clip-then-mask, matching the reference gather).
__device__ __forceinline__ float bilin_t(const __hip_bfloat16* __restrict__ base,
                                         float ix, float iy, int lane) {
  float x0f = floorf(ix), y0f = floorf(iy);
  float wx = ix - x0f, wy = iy - y0f;
  int x0 = (int)x0f, y0 = (int)y0f;
  int x1 = x0 + 1, y1 = y0 + 1;
  float mx0 = (x0 >= 0 && x0 < W) ? 1.0f : 0.0f;
  float mx1 = (x1 >= 0 && x1 < W) ? 1.0f : 0.0f;
  float my0 = (y0 >= 0 && y0 < H) ? 1.0f : 0.0f;
  float my1 = (y1 >= 0 && y1 < H) ? 1.0f : 0.0f;
  int cx0 = min(max(x0, 0), W - 1);
  int cx1 = min(max(x1, 0), W - 1);
  int cy0 = min(max(y0, 0), H - 1);
  int cy1 = min(max(y1, 0), H - 1);
  // Each load: wave-uniform pixel, lane=channel -> one 128B contiguous read.
  float v00 = __bfloat162float(base[((size_t)cy0 * W + cx0) * C + lane]) * (my0 * mx0);
  float v01 = __bfloat162float(base[((size_t)cy0 * W + cx1) * C + lane]) * (my0 * mx1);
  float v10 = __bfloat162float(base[((size_t)cy1 * W + cx0) * C + lane]) * (my1 * mx0);
  float v11 = __bfloat162float(base[((size_t)cy1 * W + cx1) * C + lane]) * (my1 * mx1);
  return v00 * (1.0f - wx) * (1.0f - wy) + v01 * wx * (1.0f - wy)
       + v10 * (1.0f - wx) * wy          + v11 * wx * wy;
}

// ---------------------------------------------------------------------------
// Batch 0: warp-affine agents 0..4 (from xt), masked channelwise max ->
// lidar[p][c], cam[p][c] (f32 pixel-major).  One wave per pixel, lane=channel.
// ---------------------------------------------------------------------------
__global__ __launch_bounds__(256) void warp_max_b0(
    const __hip_bfloat16* __restrict__ xt, const float* __restrict__ tmat,
    const int* __restrict__ ind,
    float* __restrict__ lidar, float* __restrict__ cam) {
  int t    = blockIdx.x * 256 + threadIdx.x;
  int lane = t & 63;
  int p    = t >> 6;
  int w = p & (W - 1);
  int h = p >> 8;
  float xs = (2.0f * w + 1.0f) / (float)W - 1.0f;
  float ys = (2.0f * h + 1.0f) / (float)H - 1.0f;
  float lid = -FLT_MAX, cm = -FLT_MAX;
#pragma unroll
  for (int n = 0; n < 5; ++n) {
    const float* M = tmat + n * 6;    // pairwise_t_matrix[0,0,n]
    float gx = M[0] * xs + M[1] * ys + M[2];
    float gy = M[3] * xs + M[4] * ys + M[5];
    float ix = ((gx + 1.0f) * (float)W - 1.0f) * 0.5f;
    float iy = ((gy + 1.0f) * (float)H - 1.0f) * 0.5f;
    float v = bilin_t(xt + (size_t)n * HW * C, ix, iy, lane);
    if (ind[n]) lid = fmaxf(lid, v); else cm = fmaxf(cm, v);
  }
  lidar[(size_t)p * C + lane] = lid;   // 256B coalesced
  cam[(size_t)p * C + lane]   = cm;
}

// ---------------------------------------------------------------------------
// Batch 0 attention: wave per pixel, lane=channel; 9 keys = (C,H)-rolls of cam.
// ---------------------------------------------------------------------------
__global__ __launch_bounds__(256) void attn_b0(
    const float* __restrict__ lidar, const float* __restrict__ cam,
    float* __restrict__ out) {
  int p    = (blockIdx.x * 256 + threadIdx.x) >> 6;
  int lane = threadIdx.x & 63;
  int w = p & (W - 1);
  int h = p >> 8;

  float q = lidar[(size_t)p * C + lane];

  float row[3];
#pragma unroll
  for (int dyi = 0; dyi < 3; ++dyi) {
    int dy = dyi - 1;
    int hh = (h - dy + H) & (H - 1);
    row[dyi] = cam[((size_t)hh * W + w) * C + lane];
  }

  float key[9];
#pragma unroll
  for (int dxi = 0; dxi < 3; ++dxi) {
    int dx = dxi - 1;
    int sl = (lane - dx) & 63;
#pragma unroll
    for (int dyi = 0; dyi < 3; ++dyi)
      key[dxi * 3 + dyi] = __shfl(row[dyi], sl);
  }

  float s[9];
#pragma unroll
  for (int r = 0; r < 9; ++r) s[r] = q * key[r];
#pragma unroll
  for (int m = 1; m < 64; m <<= 1) {
#pragma unroll
    for (int r = 0; r < 9; ++r) s[r] += __shfl_xor(s[r], m);
  }
#pragma unroll
  for (int r = 0; r < 9; ++r) s[r] *= 0.125f;   // 1/sqrt(64)

  float mx = s[0];
#pragma unroll
  for (int r = 1; r < 9; ++r) mx = fmaxf(mx, s[r]);
  float e[9], sum = 0.0f;
#pragma unroll
  for (int r = 0; r < 9; ++r) { e[r] = __expf(s[r] - mx); sum += e[r]; }
  float inv = 1.0f / sum;

  float o = 0.0f;
#pragma unroll
  for (int r = 0; r < 9; ++r) o += e[r] * inv * key[r];

  out[(size_t)lane * HW + p] = fmaxf(o, q);
}

// ---------------------------------------------------------------------------
// Batch 1 (all lidar): warp (from xt, agents 5..9 staged at offset 0) +
// 5-way self-attention, row 0 only.
// ---------------------------------------------------------------------------
__global__ __launch_bounds__(256) void attn_b1(
    const __hip_bfloat16* __restrict__ xt, const float* __restrict__ tmat,
    float* __restrict__ out) {
  int t    = blockIdx.x * 256 + threadIdx.x;
  int lane = t & 63;
  int p    = t >> 6;
  int w = p & (W - 1);
  int h = p >> 8;
  float xs = (2.0f * w + 1.0f) / (float)W - 1.0f;
  float ys = (2.0f * h + 1.0f) / (float)H - 1.0f;

  float v[5];
#pragma unroll
  for (int j = 0; j < 5; ++j) {
    const float* M = tmat + (25 + j) * 6;   // pairwise_t_matrix[1,0,j]
    float gx = M[0] * xs + M[1] * ys + M[2];
    float gy = M[3] * xs + M[4] * ys + M[5];
    float ix = ((gx + 1.0f) * (float)W - 1.0f) * 0.5f;
    float iy = ((gy + 1.0f) * (float)H - 1.0f) * 0.5f;
    v[j] = bilin_t(xt + (size_t)j * HW * C, ix, iy, lane);
  }

  float s[5];
#pragma unroll
  for (int j = 0; j < 5; ++j) s[j] = v[0] * v[j];
#pragma unroll
  for (int m = 1; m < 64; m <<= 1) {
#pragma unroll
    for (int j = 0; j < 5; ++j) s[j] += __shfl_xor(s[j], m);
  }
#pragma unroll
  for (int j = 0; j < 5; ++j) s[j] *= 0.125f;

  float mx = s[0];
#pragma unroll
  for (int j = 1; j < 5; ++j) mx = fmaxf(mx, s[j]);
  float e[5], sum = 0.0f;
#pragma unroll
  for (int j = 0; j < 5; ++j) { e[j] = __expf(s[j] - mx); sum += e[j]; }
  float inv = 1.0f / sum;

  float o = 0.0f;
#pragma unroll
  for (int j = 0; j < 5; ++j) o += e[j] * inv * v[j];

  out[(size_t)C * HW + (size_t)lane * HW + p] = o;
}

extern "C" void kernel_launch(void* const* d_in, const int* in_sizes, int n_in,
                              void* d_out, int out_size, void* d_ws, size_t ws_size,
                              hipStream_t stream) {
  const float* x    = (const float*)d_in[0];
  const float* tmat = (const float*)d_in[2];
  const int*   ind  = (const int*)d_in[3];
  float* out = (float*)d_out;

  // ws layout: xt bf16 [5][HW][64] (reused for both batches) | lidar | cam
  __hip_bfloat16* xt = (__hip_bfloat16*)d_ws;              // 20.97 MB
  float* lidar = (float*)((char*)d_ws + (size_t)5 * HW * C * sizeof(__hip_bfloat16));
  float* cam   = lidar + (size_t)HW * C;                   // 8.39 MB each

  transpose_cp<<<2560, 256, 0, stream>>>(x, xt, 0);        // agents 0..4
  warp_max_b0 <<<8192, 256, 0, stream>>>(xt, tmat, ind, lidar, cam);
  attn_b0     <<<8192, 256, 0, stream>>>(lidar, cam, out);
  transpose_cp<<<2560, 256, 0, stream>>>(x, xt, 5);        // agents 5..9 (after warp_max_b0)
  attn_b1     <<<8192, 256, 0, stream>>>(xt, tmat, out);
}